// Round 4
// baseline (163.877 us; speedup 1.0000x reference)
//
#include <hip/hip_runtime.h>

#define NTHREADS  256
#define STRIDE    85            // 5 + NUM_CLASSES
#define SSPAN     2704          // 52*52
#define NEG_HUGE  -3.0e38f

__device__ __forceinline__ float wave_reduce(float v) {
    #pragma unroll
    for (int off = 32; off > 0; off >>= 1)
        v += __shfl_down(v, off, 64);
    return v;
}

__global__ __launch_bounds__(NTHREADS) void loss_partial(
    const float* __restrict__ pred, const float* __restrict__ tgt,
    const float* __restrict__ anchors, float* __restrict__ partial,
    int n_cells, int ngroups)
{
    __shared__ float red[4][6];

    const int tid  = threadIdx.x;
    const int lane = tid & 63;
    const int wid  = tid >> 6;

    const float aw0 = anchors[0], ah0 = anchors[1];
    const float aw1 = anchors[2], ah1 = anchors[3];
    const float aw2 = anchors[4], ah2 = anchors[5];

    float a_obj = 0.f, a_nobj = 0.f, a_bceo = 0.f, a_bceno = 0.f,
          a_box = 0.f, a_cls = 0.f;

    const int gstride = gridDim.x * 4;
    for (int g = blockIdx.x * 4 + wid; g < ngroups; g += gstride) {
        const int cbase = g * 64;
        const int cell  = cbase + lane;
        const bool valid = cell < n_cells;

        // per-lane: own cell's target record + obj logit
        float t0 = -1.f, t1 = 0.f, t2 = 0.f, t3 = 0.f, t4 = 0.f, t5 = 0.f;
        float p0 = 0.f;
        if (valid) {
            const float* tc = tgt + (size_t)cell * 6;
            t0 = tc[0]; t1 = tc[1]; t2 = tc[2];
            t3 = tc[3]; t4 = tc[4]; t5 = tc[5];
            p0 = pred[(size_t)cell * STRIDE];
        }
        const float bce_base = fmaxf(p0, 0.f) + log1pf(__expf(-fabsf(p0)));
        if (t0 == 0.0f) { a_nobj += 1.f; a_bceno += bce_base; }
        if (t0 == 1.0f) { a_obj  += 1.f; }

        unsigned long long m = __ballot(t0 == 1.0f);

        // cooperative obj-cell loop, 2-deep pipelined record loads
        int c0 = -1; float f1a = 0.f, f2a = 0.f;
        if (m) {
            c0 = __ffsll(m) - 1; m &= m - 1;
            const float* b = pred + (size_t)(cbase + c0) * STRIDE;
            f1a = b[1 + lane];                 // floats 1..64 of record
            if (lane < 20) f2a = b[65 + lane]; // floats 65..84
        }
        while (c0 >= 0) {
            int c1 = -1; float f1b = 0.f, f2b = 0.f;
            if (m) {
                c1 = __ffsll(m) - 1; m &= m - 1;
                const float* b = pred + (size_t)(cbase + c1) * STRIDE;
                f1b = b[1 + lane];
                if (lane < 20) f2b = b[65 + lane];
            }
            // ---- process cell c0 (all lanes uniform) ----
            {
                const int cg = cbase + c0;
                // class logits: record idx 5..84.
                // f1a lane l -> idx 1+l (classes for l>=4); f2a lane l -> idx 65+l (l<20)
                const float m1 = (lane >= 4) ? f1a : NEG_HUGE;
                const float m2 = (lane < 20) ? f2a : NEG_HUGE;
                float mx = fmaxf(m1, m2);
                #pragma unroll
                for (int o = 32; o; o >>= 1) mx = fmaxf(mx, __shfl_xor(mx, o, 64));
                float e = ((lane >= 4) ? __expf(f1a - mx) : 0.f)
                        + ((lane < 20) ? __expf(f2a - mx) : 0.f);
                #pragma unroll
                for (int o = 32; o; o >>= 1) e += __shfl_xor(e, o, 64);

                // cell-c0 scalars gathered from owning lane
                const float tb1 = __shfl(t1, c0, 64), tb2 = __shfl(t2, c0, 64);
                const float tb3 = __shfl(t3, c0, 64), tb4 = __shfl(t4, c0, 64);
                const float tb5 = __shfl(t5, c0, 64);
                const float pb0 = __shfl(p0, c0, 64);
                const float bb  = __shfl(bce_base, c0, 64);
                // box logits from cooperative load (record idx 1..4 = lanes 0..3)
                const float pp1 = __shfl(f1a, 0, 64), pp2 = __shfl(f1a, 1, 64);
                const float pp3 = __shfl(f1a, 2, 64), pp4 = __shfl(f1a, 3, 64);

                const int   label = (int)tb5;
                const int   idx   = 5 + label;          // 5..84
                const float s1 = __shfl(f1a, (idx - 1) & 63, 64);
                const float s2 = __shfl(f2a, (idx - 65) & 63, 64);
                const float lv = (idx <= 64) ? s1 : s2;

                const int aidx = (cg / SSPAN) % 3;
                const float aw = aidx == 0 ? aw0 : (aidx == 1 ? aw1 : aw2);
                const float ah = aidx == 0 ? ah0 : (aidx == 1 ? ah1 : ah2);

                const float sx = 1.f / (1.f + __expf(-pp1));
                const float sy = 1.f / (1.f + __expf(-pp2));
                const float pw = __expf(pp3) * aw, ph = __expf(pp4) * ah;
                const float b1x1 = sx - pw * 0.5f, b1x2 = sx + pw * 0.5f;
                const float b1y1 = sy - ph * 0.5f, b1y2 = sy + ph * 0.5f;
                const float b2x1 = tb1 - tb3 * 0.5f, b2x2 = tb1 + tb3 * 0.5f;
                const float b2y1 = tb2 - tb4 * 0.5f, b2y2 = tb2 + tb4 * 0.5f;
                const float iw = fmaxf(fminf(b1x2, b2x2) - fmaxf(b1x1, b2x1), 0.f);
                const float ih = fmaxf(fminf(b1y2, b2y2) - fmaxf(b1y1, b2y1), 0.f);
                const float inter = iw * ih;
                const float uni = (b1x2 - b1x1) * (b1y2 - b1y1)
                                + (b2x2 - b2x1) * (b2y2 - b2y1) - inter;
                const float iou = inter / (uni + 1e-16f);

                const float vbceo = bb - pb0 * iou;
                const float lw = logf(1e-16f + tb3 / aw);
                const float lh = logf(1e-16f + tb4 / ah);
                const float d0 = sx - tb1, d1 = sy - tb2;
                const float d2 = pp3 - lw, d3 = pp4 - lh;
                const float vbox = d0 * d0 + d1 * d1 + d2 * d2 + d3 * d3;
                const float vcls = (mx + __logf(e)) - lv;

                if (lane == c0) {
                    a_bceo += vbceo;
                    a_box  += vbox;
                    a_cls  += vcls;
                }
            }
            c0 = c1; f1a = f1b; f2a = f2b;
        }
    }

    // ---- block reduction -> per-block partial ----
    float vals[6] = {a_obj, a_nobj, a_bceo, a_bceno, a_box, a_cls};
    #pragma unroll
    for (int k = 0; k < 6; ++k) {
        const float r = wave_reduce(vals[k]);
        if (lane == 0) red[wid][k] = r;
    }
    __syncthreads();
    if (tid == 0) {
        #pragma unroll
        for (int k = 0; k < 6; ++k)
            partial[blockIdx.x * 6 + k] =
                red[0][k] + red[1][k] + red[2][k] + red[3][k];
    }
}

__global__ __launch_bounds__(NTHREADS) void loss_final(
    const float* __restrict__ partial, int nblocks, float* __restrict__ out)
{
    __shared__ float red[4][6];
    const int tid = threadIdx.x, lane = tid & 63, wid = tid >> 6;
    float s[6] = {0.f, 0.f, 0.f, 0.f, 0.f, 0.f};
    for (int i = tid; i < nblocks; i += NTHREADS) {
        #pragma unroll
        for (int k = 0; k < 6; ++k) s[k] += partial[i * 6 + k];
    }
    #pragma unroll
    for (int k = 0; k < 6; ++k) {
        const float r = wave_reduce(s[k]);
        if (lane == 0) red[wid][k] = r;
    }
    __syncthreads();
    if (tid == 0) {
        float t[6];
        #pragma unroll
        for (int k = 0; k < 6; ++k)
            t[k] = red[0][k] + red[1][k] + red[2][k] + red[3][k];
        const float n_obj = t[0], n_noobj = t[1];
        out[0] = t[2] / n_obj + t[3] / n_noobj
               + t[4] / (4.f * n_obj) + t[5] / n_obj;
    }
}

extern "C" void kernel_launch(void* const* d_in, const int* in_sizes, int n_in,
                              void* d_out, int out_size, void* d_ws, size_t ws_size,
                              hipStream_t stream) {
    const float* pred    = (const float*)d_in[0];
    const float* tgt     = (const float*)d_in[1];
    const float* anchors = (const float*)d_in[2];
    float* out = (float*)d_out;

    const int n_cells = in_sizes[1] / 6;                 // 259584
    const int ngroups = (n_cells + 63) / 64;             // 4056
    int grid = (ngroups + 3) / 4;                        // 1 group per wave
    if (grid > 2048) grid = 2048;
    if (grid < 1)    grid = 1;
    float* partial = (float*)d_ws;

    loss_partial<<<grid, NTHREADS, 0, stream>>>(pred, tgt, anchors, partial,
                                                n_cells, ngroups);
    loss_final<<<1, NTHREADS, 0, stream>>>(partial, grid, out);
}

// Round 9
// 135.943 us; speedup vs baseline: 1.2055x; 1.2055x over previous
//
#include <hip/hip_runtime.h>

#define NTHREADS  256
#define TILE      256           // cells per block-tile (== NTHREADS)
#define STRIDE    85            // 5 + NUM_CLASSES
#define SSPAN     2704          // 52*52
#define MAXGRID   2048

__device__ __forceinline__ float wave_reduce(float v) {
    #pragma unroll
    for (int off = 32; off > 0; off >>= 1)
        v += __shfl_down(v, off, 64);
    return v;
}

__global__ __launch_bounds__(NTHREADS) void loss_partial(
    const float* __restrict__ pred, const float* __restrict__ tgt,
    const float* __restrict__ anchors, float* __restrict__ partial,
    int n_cells, int n_tiles)
{
    __shared__ int   qcell[TILE];
    __shared__ int   qlab [TILE];
    __shared__ float qt1[TILE], qt2[TILE], qt3[TILE], qt4[TILE];
    __shared__ float qp0[TILE], qbb[TILE];
    __shared__ int   wcnt[4];
    __shared__ float red[4][6];

    const int tid  = threadIdx.x;
    const int lane = tid & 63;
    const int wid  = tid >> 6;
    const int part = tid & 3;

    const float aw0 = anchors[0], ah0 = anchors[1];
    const float aw1 = anchors[2], ah1 = anchors[3];
    const float aw2 = anchors[4], ah2 = anchors[5];

    float a_obj = 0.f, a_nobj = 0.f, a_bceo = 0.f, a_bceno = 0.f,
          a_box = 0.f, a_cls = 0.f;

    for (int tile = blockIdx.x; tile < n_tiles; tile += gridDim.x) {
        const int cell  = tile * TILE + tid;
        const bool valid = cell < n_cells;

        // ---- phase 1: dense scan (own cell) ----
        float t0 = -1.f, t1 = 0.f, t2 = 0.f, t3 = 0.f, t4 = 0.f, t5 = 0.f;
        float p0 = 0.f;
        if (valid) {
            const float2* tc2 = (const float2*)(tgt + (size_t)cell * 6);
            const float2 a = tc2[0], b = tc2[1], c = tc2[2];
            t0 = a.x; t1 = a.y; t2 = b.x; t3 = b.y; t4 = c.x; t5 = c.y;
            p0 = pred[(size_t)cell * STRIDE];
        }
        const float bce_base = fmaxf(p0, 0.f) + log1pf(__expf(-fabsf(p0)));
        if (t0 == 0.0f) { a_nobj += 1.f; a_bceno += bce_base; }
        const bool isobj = (t0 == 1.0f);
        if (isobj) a_obj += 1.f;

        // ---- compact obj cells into LDS queue ----
        const unsigned long long m = __ballot(isobj);
        if (lane == 0) wcnt[wid] = __popcll(m);
        __syncthreads();
        int off = 0;
        #pragma unroll
        for (int w = 0; w < 4; ++w) if (w < wid) off += wcnt[w];
        const int nq = wcnt[0] + wcnt[1] + wcnt[2] + wcnt[3];
        if (isobj) {
            const int rank = off + __popcll(m & ((1ull << lane) - 1ull));
            qcell[rank] = cell;
            qt1[rank] = t1; qt2[rank] = t2; qt3[rank] = t3; qt4[rank] = t4;
            qlab[rank] = (int)t5;
            qp0[rank]  = p0;
            qbb[rank]  = bce_base;
        }
        __syncthreads();

        // ---- phase 2: parallel obj processing, 64 cells/round ----
        const int nr = (nq + 63) >> 6;
        for (int r = 0; r < nr; ++r) {
            const int qi  = r * 64 + (tid >> 2);
            const bool act = qi < nq;
            const int cellg = act ? qcell[qi] : 0;
            const float* pc = pred + (size_t)cellg * STRIDE;

            float v[20];
            const float* cp = pc + 5 + part * 20;
            #pragma unroll
            for (int k = 0; k < 20; ++k) v[k] = cp[k];
            float mx = v[0];
            #pragma unroll
            for (int k = 1; k < 20; ++k) mx = fmaxf(mx, v[k]);
            mx = fmaxf(mx, __shfl_xor(mx, 1, 4));
            mx = fmaxf(mx, __shfl_xor(mx, 2, 4));
            float se = 0.f;
            #pragma unroll
            for (int k = 0; k < 20; ++k) se += __expf(v[k] - mx);
            se += __shfl_xor(se, 1, 4);
            se += __shfl_xor(se, 2, 4);

            const float pp  = pc[1 + part];
            const float pp1 = __shfl(pp, 0, 4), pp2 = __shfl(pp, 1, 4);
            const float pp3 = __shfl(pp, 2, 4), pp4 = __shfl(pp, 3, 4);

            if (part == 0 && act) {
                const float tb1 = qt1[qi], tb2 = qt2[qi];
                const float tb3 = qt3[qi], tb4 = qt4[qi];
                const int   label = qlab[qi];
                const float pb0 = qp0[qi], bb = qbb[qi];
                const float lv  = pc[5 + label];

                const int aidx = (cellg / SSPAN) % 3;
                const float aw = aidx == 0 ? aw0 : (aidx == 1 ? aw1 : aw2);
                const float ah = aidx == 0 ? ah0 : (aidx == 1 ? ah1 : ah2);

                const float sx = 1.f / (1.f + __expf(-pp1));
                const float sy = 1.f / (1.f + __expf(-pp2));
                const float pw = __expf(pp3) * aw, ph = __expf(pp4) * ah;
                const float b1x1 = sx - pw * 0.5f, b1x2 = sx + pw * 0.5f;
                const float b1y1 = sy - ph * 0.5f, b1y2 = sy + ph * 0.5f;
                const float b2x1 = tb1 - tb3 * 0.5f, b2x2 = tb1 + tb3 * 0.5f;
                const float b2y1 = tb2 - tb4 * 0.5f, b2y2 = tb2 + tb4 * 0.5f;
                const float iw = fmaxf(fminf(b1x2, b2x2) - fmaxf(b1x1, b2x1), 0.f);
                const float ih = fmaxf(fminf(b1y2, b2y2) - fmaxf(b1y1, b2y1), 0.f);
                const float inter = iw * ih;
                const float uni = (b1x2 - b1x1) * (b1y2 - b1y1)
                                + (b2x2 - b2x1) * (b2y2 - b2y1) - inter;
                const float iou = inter / (uni + 1e-16f);

                a_bceo += bb - pb0 * iou;
                const float lw = logf(1e-16f + tb3 / aw);
                const float lh = logf(1e-16f + tb4 / ah);
                const float d0 = sx - tb1, d1 = sy - tb2;
                const float d2 = pp3 - lw, d3 = pp4 - lh;
                a_box += d0 * d0 + d1 * d1 + d2 * d2 + d3 * d3;
                a_cls += (mx + __logf(se)) - lv;
            }
        }
        __syncthreads();   // queue reusable next tile
    }

    // ---- block reduction -> per-block partial ----
    float vals[6] = {a_obj, a_nobj, a_bceo, a_bceno, a_box, a_cls};
    #pragma unroll
    for (int k = 0; k < 6; ++k) {
        const float r = wave_reduce(vals[k]);
        if (lane == 0) red[wid][k] = r;
    }
    __syncthreads();
    if (tid == 0) {
        #pragma unroll
        for (int k = 0; k < 6; ++k)
            partial[blockIdx.x * 6 + k] =
                red[0][k] + red[1][k] + red[2][k] + red[3][k];
    }
}

__global__ __launch_bounds__(NTHREADS) void loss_final(
    const float* __restrict__ partial, int nblocks, float* __restrict__ out)
{
    __shared__ float red[4][6];
    const int tid = threadIdx.x, lane = tid & 63, wid = tid >> 6;
    float s[6] = {0.f, 0.f, 0.f, 0.f, 0.f, 0.f};
    for (int i = tid; i < nblocks; i += NTHREADS) {
        #pragma unroll
        for (int k = 0; k < 6; ++k) s[k] += partial[i * 6 + k];
    }
    #pragma unroll
    for (int k = 0; k < 6; ++k) {
        const float r = wave_reduce(s[k]);
        if (lane == 0) red[wid][k] = r;
    }
    __syncthreads();
    if (tid == 0) {
        float t[6];
        #pragma unroll
        for (int k = 0; k < 6; ++k)
            t[k] = red[0][k] + red[1][k] + red[2][k] + red[3][k];
        const float n_obj = t[0], n_noobj = t[1];
        out[0] = t[2] / n_obj + t[3] / n_noobj
               + t[4] / (4.f * n_obj) + t[5] / n_obj;
    }
}

extern "C" void kernel_launch(void* const* d_in, const int* in_sizes, int n_in,
                              void* d_out, int out_size, void* d_ws, size_t ws_size,
                              hipStream_t stream) {
    const float* pred    = (const float*)d_in[0];
    const float* tgt     = (const float*)d_in[1];
    const float* anchors = (const float*)d_in[2];
    float* out = (float*)d_out;

    const int n_cells = in_sizes[1] / 6;                 // 259584
    const int n_tiles = (n_cells + TILE - 1) / TILE;     // 1014
    int grid = n_tiles < MAXGRID ? n_tiles : MAXGRID;
    if (grid < 1) grid = 1;
    float* partial = (float*)d_ws;

    loss_partial<<<grid, NTHREADS, 0, stream>>>(pred, tgt, anchors, partial,
                                                n_cells, n_tiles);
    loss_final<<<1, NTHREADS, 0, stream>>>(partial, grid, out);
}

// Round 10
// 134.217 us; speedup vs baseline: 1.2210x; 1.0129x over previous
//
#include <hip/hip_runtime.h>

#define NTHREADS  256
#define TILE      256           // cells per block-tile (== NTHREADS)
#define STRIDE    85            // 5 + NUM_CLASSES
#define SSPAN     2704          // 52*52
#define MAXGRID   2048
#define NEG_HUGE  -3.0e38f

#define ELEM(v,e) ((e)==0?(v).x:(e)==1?(v).y:(e)==2?(v).z:(v).w)

__device__ __forceinline__ float wave_reduce(float v) {
    #pragma unroll
    for (int off = 32; off > 0; off >>= 1)
        v += __shfl_down(v, off, 64);
    return v;
}

__global__ __launch_bounds__(NTHREADS) void loss_partial(
    const float* __restrict__ pred, const float* __restrict__ tgt,
    const float* __restrict__ anchors, float* __restrict__ partial,
    int n_cells, int n_tiles)
{
    __shared__ int   qcell[TILE];
    __shared__ int   qlab [TILE];
    __shared__ float qt1[TILE], qt2[TILE], qt3[TILE], qt4[TILE];
    __shared__ float qp0[TILE], qbb[TILE];
    __shared__ int   wcnt[4];
    __shared__ float red[4][6];

    const int tid  = threadIdx.x;
    const int lane = tid & 63;
    const int wid  = tid >> 6;
    const int part = tid & 3;
    const int slot = tid >> 2;   // 0..63: cell-group within block

    const float aw0 = anchors[0], ah0 = anchors[1];
    const float aw1 = anchors[2], ah1 = anchors[3];
    const float aw2 = anchors[4], ah2 = anchors[5];

    float a_obj = 0.f, a_nobj = 0.f, a_bceo = 0.f, a_bceno = 0.f,
          a_box = 0.f, a_cls = 0.f;

    for (int tile = blockIdx.x; tile < n_tiles; tile += gridDim.x) {
        const int cell  = tile * TILE + tid;
        const bool valid = cell < n_cells;

        // ---- phase 1: dense scan (own cell) ----
        float t0 = -1.f, t1 = 0.f, t2 = 0.f, t3 = 0.f, t4 = 0.f, t5 = 0.f;
        float p0 = 0.f;
        if (valid) {
            const float2* tc2 = (const float2*)(tgt + (size_t)cell * 6);
            const float2 a = tc2[0], b = tc2[1], c = tc2[2];
            t0 = a.x; t1 = a.y; t2 = b.x; t3 = b.y; t4 = c.x; t5 = c.y;
            p0 = pred[(size_t)cell * STRIDE];
        }
        const float bce_base = fmaxf(p0, 0.f) + log1pf(__expf(-fabsf(p0)));
        if (t0 == 0.0f) { a_nobj += 1.f; a_bceno += bce_base; }
        const bool isobj = (t0 == 1.0f);
        if (isobj) a_obj += 1.f;

        // ---- compact obj cells into LDS queue ----
        const unsigned long long m = __ballot(isobj);
        if (lane == 0) wcnt[wid] = __popcll(m);
        __syncthreads();
        int off = 0;
        #pragma unroll
        for (int w = 0; w < 4; ++w) if (w < wid) off += wcnt[w];
        const int nq = wcnt[0] + wcnt[1] + wcnt[2] + wcnt[3];
        if (isobj) {
            const int rank = off + __popcll(m & ((1ull << lane) - 1ull));
            qcell[rank] = cell;
            qt1[rank] = t1; qt2[rank] = t2; qt3[rank] = t3; qt4[rank] = t4;
            qlab[rank] = (int)t5;
            qp0[rank]  = p0;
            qbb[rank]  = bce_base;
        }
        __syncthreads();

        // ---- phase 2: parallel obj processing, 64 cells/round,
        //      vectorized aligned float4 record reads + 1-deep prefetch ----
        const int nr = (nq + 63) >> 6;

        float4 qA[5] = {}; float ppA = 0.f, e84A = 0.f; int cgA = 0, qiA = 0; bool actA = false;
        float4 qB[5] = {}; float ppB = 0.f, e84B = 0.f; int cgB = 0, qiB = 0; bool actB = false;

        auto loadR = [&](int r, float4 (&q)[5], float& pp, float& e84,
                         int& cg, int& qi, bool& act) {
            qi  = r * 64 + slot;
            act = qi < nq;
            cg  = qcell[act ? qi : 0];
            const float* pc = pred + (size_t)cg * STRIDE;
            // floats [4+20*part .. 23+20*part]; offset 4+20p ≡ 0 mod 4 -> 16B aligned
            const float4* v4 = (const float4*)(pc + 4 + part * 20);
            #pragma unroll
            for (int j = 0; j < 5; ++j) q[j] = v4[j];
            pp  = pc[1 + part];   // box logits 1..4
            e84 = pc[84];         // last class (counted by part 3 only)
        };

        if (nr > 0) loadR(0, qA, ppA, e84A, cgA, qiA, actA);
        for (int r = 0; r < nr; ++r) {
            if (r + 1 < nr) loadR(r + 1, qB, ppB, e84B, cgB, qiB, actB);

            // ---- softmax over the 80 classes (float 4 masked for part 0) ----
            float mx = (part == 0) ? NEG_HUGE : qA[0].x;
            #pragma unroll
            for (int j = 0; j < 5; ++j) {
                #pragma unroll
                for (int e = 0; e < 4; ++e)
                    if (!(j == 0 && e == 0)) mx = fmaxf(mx, ELEM(qA[j], e));
            }
            mx = fmaxf(mx, (part == 3) ? e84A : NEG_HUGE);
            mx = fmaxf(mx, __shfl_xor(mx, 1, 4));
            mx = fmaxf(mx, __shfl_xor(mx, 2, 4));
            float se = (part == 0) ? 0.f : __expf(qA[0].x - mx);
            #pragma unroll
            for (int j = 0; j < 5; ++j) {
                #pragma unroll
                for (int e = 0; e < 4; ++e)
                    if (!(j == 0 && e == 0)) se += __expf(ELEM(qA[j], e) - mx);
            }
            se += (part == 3) ? __expf(e84A - mx) : 0.f;
            se += __shfl_xor(se, 1, 4);
            se += __shfl_xor(se, 2, 4);

            const float pp1 = __shfl(ppA, 0, 4), pp2 = __shfl(ppA, 1, 4);
            const float pp3 = __shfl(ppA, 2, 4), pp4 = __shfl(ppA, 3, 4);

            if (part == 0 && actA) {
                const int qi = qiA, cellg = cgA;
                const float* pc = pred + (size_t)cellg * STRIDE;
                const float tb1 = qt1[qi], tb2 = qt2[qi];
                const float tb3 = qt3[qi], tb4 = qt4[qi];
                const int   label = qlab[qi];
                const float pb0 = qp0[qi], bb = qbb[qi];
                const float lv  = pc[5 + label];   // L1 hit: quad just fetched this line

                const int aidx = (cellg / SSPAN) % 3;
                const float aw = aidx == 0 ? aw0 : (aidx == 1 ? aw1 : aw2);
                const float ah = aidx == 0 ? ah0 : (aidx == 1 ? ah1 : ah2);

                const float sx = 1.f / (1.f + __expf(-pp1));
                const float sy = 1.f / (1.f + __expf(-pp2));
                const float pw = __expf(pp3) * aw, ph = __expf(pp4) * ah;
                const float b1x1 = sx - pw * 0.5f, b1x2 = sx + pw * 0.5f;
                const float b1y1 = sy - ph * 0.5f, b1y2 = sy + ph * 0.5f;
                const float b2x1 = tb1 - tb3 * 0.5f, b2x2 = tb1 + tb3 * 0.5f;
                const float b2y1 = tb2 - tb4 * 0.5f, b2y2 = tb2 + tb4 * 0.5f;
                const float iw = fmaxf(fminf(b1x2, b2x2) - fmaxf(b1x1, b2x1), 0.f);
                const float ih = fmaxf(fminf(b1y2, b2y2) - fmaxf(b1y1, b2y1), 0.f);
                const float inter = iw * ih;
                const float uni = (b1x2 - b1x1) * (b1y2 - b1y1)
                                + (b2x2 - b2x1) * (b2y2 - b2y1) - inter;
                const float iou = inter / (uni + 1e-16f);

                a_bceo += bb - pb0 * iou;
                const float lw = logf(1e-16f + tb3 / aw);
                const float lh = logf(1e-16f + tb4 / ah);
                const float d0 = sx - tb1, d1 = sy - tb2;
                const float d2 = pp3 - lw, d3 = pp4 - lh;
                a_box += d0 * d0 + d1 * d1 + d2 * d2 + d3 * d3;
                a_cls += (mx + __logf(se)) - lv;
            }

            // shift pipeline B -> A (static register moves)
            #pragma unroll
            for (int j = 0; j < 5; ++j) qA[j] = qB[j];
            ppA = ppB; e84A = e84B; cgA = cgB; qiA = qiB; actA = actB;
        }
        __syncthreads();   // queue reusable next tile
    }

    // ---- block reduction -> per-block partial ----
    float vals[6] = {a_obj, a_nobj, a_bceo, a_bceno, a_box, a_cls};
    #pragma unroll
    for (int k = 0; k < 6; ++k) {
        const float r = wave_reduce(vals[k]);
        if (lane == 0) red[wid][k] = r;
    }
    __syncthreads();
    if (tid == 0) {
        #pragma unroll
        for (int k = 0; k < 6; ++k)
            partial[blockIdx.x * 6 + k] =
                red[0][k] + red[1][k] + red[2][k] + red[3][k];
    }
}

__global__ __launch_bounds__(NTHREADS) void loss_final(
    const float* __restrict__ partial, int nblocks, float* __restrict__ out)
{
    __shared__ float red[4][6];
    const int tid = threadIdx.x, lane = tid & 63, wid = tid >> 6;
    float s[6] = {0.f, 0.f, 0.f, 0.f, 0.f, 0.f};
    for (int i = tid; i < nblocks; i += NTHREADS) {
        #pragma unroll
        for (int k = 0; k < 6; ++k) s[k] += partial[i * 6 + k];
    }
    #pragma unroll
    for (int k = 0; k < 6; ++k) {
        const float r = wave_reduce(s[k]);
        if (lane == 0) red[wid][k] = r;
    }
    __syncthreads();
    if (tid == 0) {
        float t[6];
        #pragma unroll
        for (int k = 0; k < 6; ++k)
            t[k] = red[0][k] + red[1][k] + red[2][k] + red[3][k];
        const float n_obj = t[0], n_noobj = t[1];
        out[0] = t[2] / n_obj + t[3] / n_noobj
               + t[4] / (4.f * n_obj) + t[5] / n_obj;
    }
}

extern "C" void kernel_launch(void* const* d_in, const int* in_sizes, int n_in,
                              void* d_out, int out_size, void* d_ws, size_t ws_size,
                              hipStream_t stream) {
    const float* pred    = (const float*)d_in[0];
    const float* tgt     = (const float*)d_in[1];
    const float* anchors = (const float*)d_in[2];
    float* out = (float*)d_out;

    const int n_cells = in_sizes[1] / 6;                 // 259584
    const int n_tiles = (n_cells + TILE - 1) / TILE;     // 1014
    int grid = n_tiles < MAXGRID ? n_tiles : MAXGRID;
    if (grid < 1) grid = 1;
    float* partial = (float*)d_ws;

    loss_partial<<<grid, NTHREADS, 0, stream>>>(pred, tgt, anchors, partial,
                                                n_cells, n_tiles);
    loss_final<<<1, NTHREADS, 0, stream>>>(partial, grid, out);
}